// Round 1
// baseline (248.693 us; speedup 1.0000x reference)
//
#include <hip/hip_runtime.h>

#define S_LEN 2048
#define D_HEAD 64
#define NBH 32

typedef unsigned short u16;
typedef __attribute__((ext_vector_type(8))) short bf16x8;
typedef __attribute__((ext_vector_type(4))) float f32x4;

#define MFMA16(A, B, C) __builtin_amdgcn_mfma_f32_16x16x32_bf16(A, B, C, 0, 0, 0)

__device__ __forceinline__ u16 f2bf(float f) {
  unsigned int u = __builtin_bit_cast(unsigned int, f);
  u += 0x7fffu + ((u >> 16) & 1u);
  return (u16)(u >> 16);
}
__device__ __forceinline__ float bf2f(u16 b) {
  unsigned int u = ((unsigned int)b) << 16;
  return __builtin_bit_cast(float, u);
}

// ---------- prep 1: Q' = Hin @ avAp[h]  (fp32), split to bf16 hi/lo ----------
__global__ __launch_bounds__(256, 2) void qproj_kernel(
    const float* __restrict__ Hin, const float* __restrict__ avAp,
    u16* __restrict__ Qhi, u16* __restrict__ Qlo) {
  __shared__ float sA[64 * 64];   // avAp[h], [d][e]
  __shared__ float sH[64 * 68];   // Hin tile, padded stride 68
  const int bh = blockIdx.y;
  const int h = bh & 15;          // bh = b*16 + h
  const int s0 = blockIdx.x * 64;
  const int tid = threadIdx.x;
  const size_t tbase = ((size_t)bh * S_LEN + s0) * D_HEAD;

#pragma unroll
  for (int i = 0; i < 4; ++i) {
    int c = tid + 256 * i;  // float4 chunk 0..1023
    *(float4*)(sA + c * 4) = *(const float4*)(avAp + (size_t)h * 4096 + c * 4);
    int row = c >> 4, col = (c & 15) * 4;
    *(float4*)(sH + row * 68 + col) = *(const float4*)(Hin + tbase + c * 4);
  }
  __syncthreads();

  const int r = tid >> 2;          // local row 0..63
  const int qd = (tid & 3) * 16;   // col base
  float acc[16];
#pragma unroll
  for (int i = 0; i < 16; ++i) acc[i] = 0.f;

  for (int d = 0; d < 64; ++d) {
    float x = sH[r * 68 + d];
    const float4* arow = (const float4*)(sA + d * 64 + qd);
#pragma unroll
    for (int c4 = 0; c4 < 4; ++c4) {
      float4 a = arow[c4];
      acc[c4 * 4 + 0] += x * a.x;
      acc[c4 * 4 + 1] += x * a.y;
      acc[c4 * 4 + 2] += x * a.z;
      acc[c4 * 4 + 3] += x * a.w;
    }
  }

  size_t ob = tbase + (size_t)r * 64 + qd;
#pragma unroll
  for (int half = 0; half < 2; ++half) {
    unsigned int wh[4], wl[4];
#pragma unroll
    for (int j = 0; j < 4; ++j) {
      int i = half * 8 + j * 2;
      u16 h0 = f2bf(acc[i]);
      u16 l0 = f2bf(acc[i] - bf2f(h0));
      u16 h1 = f2bf(acc[i + 1]);
      u16 l1 = f2bf(acc[i + 1] - bf2f(h1));
      wh[j] = (unsigned int)h0 | ((unsigned int)h1 << 16);
      wl[j] = (unsigned int)l0 | ((unsigned int)l1 << 16);
    }
    *(uint4*)(Qhi + ob + half * 8) = make_uint4(wh[0], wh[1], wh[2], wh[3]);
    *(uint4*)(Qlo + ob + half * 8) = make_uint4(wl[0], wl[1], wl[2], wl[3]);
  }
}

// ---------- prep 2: K split to bf16 hi/lo; V -> V^T bf16 [bh][d][s] ----------
__global__ __launch_bounds__(256, 2) void kvprep_kernel(
    const float* __restrict__ Hk, const float* __restrict__ Hv,
    u16* __restrict__ Khi, u16* __restrict__ Klo, u16* __restrict__ Vt) {
  __shared__ float sT[64 * 68];  // Hv tile [s][d], padded
  const int bh = blockIdx.y;
  const int s0 = blockIdx.x * 64;
  const int tid = threadIdx.x;
  const size_t base = ((size_t)bh * S_LEN + s0) * D_HEAD;

#pragma unroll
  for (int i = 0; i < 4; ++i) {
    int c = tid + 256 * i;
    float4 k4 = *(const float4*)(Hk + base + c * 4);
    u16 h0 = f2bf(k4.x), h1 = f2bf(k4.y), h2 = f2bf(k4.z), h3 = f2bf(k4.w);
    u16 l0 = f2bf(k4.x - bf2f(h0)), l1 = f2bf(k4.y - bf2f(h1));
    u16 l2 = f2bf(k4.z - bf2f(h2)), l3 = f2bf(k4.w - bf2f(h3));
    *(ushort4*)(Khi + base + c * 4) = make_ushort4(h0, h1, h2, h3);
    *(ushort4*)(Klo + base + c * 4) = make_ushort4(l0, l1, l2, l3);
    float4 v4 = *(const float4*)(Hv + base + c * 4);
    int row = c >> 4, col = (c & 15) * 4;
    *(float4*)(sT + row * 68 + col) = v4;
  }
  __syncthreads();

#pragma unroll
  for (int i = 0; i < 4; ++i) {
    int c = tid + 256 * i;        // 1024 chunks of 4 s-values
    int d = c >> 4, s4 = (c & 15) * 4;
    u16 o0 = f2bf(sT[(s4 + 0) * 68 + d]);
    u16 o1 = f2bf(sT[(s4 + 1) * 68 + d]);
    u16 o2 = f2bf(sT[(s4 + 2) * 68 + d]);
    u16 o3 = f2bf(sT[(s4 + 3) * 68 + d]);
    *(ushort4*)(Vt + ((size_t)bh * D_HEAD + d) * S_LEN + s0 + s4) =
        make_ushort4(o0, o1, o2, o3);
  }
}

// ---------- fused causal flash attention ----------
__global__ __launch_bounds__(256, 2) void attn_kernel(
    const u16* __restrict__ Qhi, const u16* __restrict__ Qlo,
    const u16* __restrict__ Khi, const u16* __restrict__ Klo,
    const u16* __restrict__ Vt, float* __restrict__ Out) {
  __shared__ u16 sKhi[64 * 64];
  __shared__ u16 sKlo[64 * 64];
  __shared__ u16 sVt[64 * 64];     // [d][kv], swizzled
  __shared__ u16 sP[4 * 16 * 64];  // per-wave P tile, swizzled

  const int bh = blockIdx.y;
  const int qtile = (int)gridDim.x - 1 - (int)blockIdx.x;  // heavy blocks first
  const int q0 = qtile * 64;
  const int tid = threadIdx.x;
  const int wave = tid >> 6;
  const int lane = tid & 63;
  const int lr = lane & 15;
  const int lg = lane >> 4;

  // Q A-fragments: lane holds Q[q0+wave*16+lr][lg*8+j (+32)]
  const int qrow = q0 + wave * 16 + lr;
  const size_t qoff = ((size_t)bh * S_LEN + qrow) * D_HEAD;
  bf16x8 qhi[2], qlo[2];
  qhi[0] = *(const bf16x8*)(Qhi + qoff + lg * 8);
  qhi[1] = *(const bf16x8*)(Qhi + qoff + 32 + lg * 8);
  qlo[0] = *(const bf16x8*)(Qlo + qoff + lg * 8);
  qlo[1] = *(const bf16x8*)(Qlo + qoff + 32 + lg * 8);

  f32x4 Oacc[4];
#pragma unroll
  for (int i = 0; i < 4; ++i) Oacc[i] = (f32x4){0.f, 0.f, 0.f, 0.f};
  float m_r[4], l_r[4];
#pragma unroll
  for (int i = 0; i < 4; ++i) { m_r[i] = -3.0e38f; l_r[i] = 0.f; }

  const int nTiles = qtile + 1;
  const bool wave_rows_max = q0 + wave * 16 + 15;  // (computed inline below)

  for (int t = 0; t < nTiles; ++t) {
    const int kv0 = t * 64;

    // ---- stage K(hi,lo) and V^T tiles into swizzled LDS ----
#pragma unroll
    for (int i = 0; i < 2; ++i) {
      int c = tid + 256 * i;          // 512 chunks of 16B
      int row = c >> 3, c16 = c & 7;  // row 0..63, 16B col 0..7
      int dst = row * 128 + ((c16 * 16) ^ ((row & 7) << 4));
      const size_t kgoff = ((size_t)bh * S_LEN + kv0 + row) * D_HEAD + c16 * 8;
      *(bf16x8*)((char*)sKhi + dst) = *(const bf16x8*)(Khi + kgoff);
      *(bf16x8*)((char*)sKlo + dst) = *(const bf16x8*)(Klo + kgoff);
      const size_t vgoff = ((size_t)bh * D_HEAD + row) * S_LEN + kv0 + c16 * 8;
      *(bf16x8*)((char*)sVt + dst) = *(const bf16x8*)(Vt + vgoff);
    }
    __syncthreads();

    const bool active = (kv0 <= q0 + wave * 16 + 15);
    if (active) {
      // ---- QK^T: S[16 q][64 kv], split-precision 3-MFMA ----
      f32x4 sacc[4];
#pragma unroll
      for (int nb = 0; nb < 4; ++nb) {
        sacc[nb] = (f32x4){0.f, 0.f, 0.f, 0.f};
#pragma unroll
        for (int kk = 0; kk < 2; ++kk) {
          int krow = nb * 16 + lr;
          int off = krow * 128 + ((kk * 64 + lg * 16) ^ ((krow & 7) << 4));
          bf16x8 kh = *(const bf16x8*)((char*)sKhi + off);
          bf16x8 kl = *(const bf16x8*)((char*)sKlo + off);
          sacc[nb] = MFMA16(qhi[kk], kh, sacc[nb]);
          sacc[nb] = MFMA16(qlo[kk], kh, sacc[nb]);
          sacc[nb] = MFMA16(qhi[kk], kl, sacc[nb]);
        }
      }

      // ---- online softmax (row q = q0+wave*16+lg*4+r lives in 16-lane group) ----
      float p[4][4];
      float tmax[4];
#pragma unroll
      for (int r = 0; r < 4; ++r) tmax[r] = -3.0e38f;
#pragma unroll
      for (int nb = 0; nb < 4; ++nb) {
#pragma unroll
        for (int r = 0; r < 4; ++r) {
          float v = sacc[nb][r] * 0.125f;  // 1/sqrt(64)
          int kvg = kv0 + nb * 16 + lr;
          int qg = q0 + wave * 16 + lg * 4 + r;
          if (kvg > qg) v = -1.0e30f;  // causal mask
          p[nb][r] = v;
          tmax[r] = fmaxf(tmax[r], v);
        }
      }
#pragma unroll
      for (int r = 0; r < 4; ++r) {
        float tm = tmax[r];
        tm = fmaxf(tm, __shfl_xor(tm, 1));
        tm = fmaxf(tm, __shfl_xor(tm, 2));
        tm = fmaxf(tm, __shfl_xor(tm, 4));
        tm = fmaxf(tm, __shfl_xor(tm, 8));
        float mnew = fmaxf(m_r[r], tm);
        float corr = __expf(m_r[r] - mnew);
        m_r[r] = mnew;
        float rs = 0.f;
#pragma unroll
        for (int nb = 0; nb < 4; ++nb) {
          p[nb][r] = __expf(p[nb][r] - mnew);
          rs += p[nb][r];
        }
        rs += __shfl_xor(rs, 1);
        rs += __shfl_xor(rs, 2);
        rs += __shfl_xor(rs, 4);
        rs += __shfl_xor(rs, 8);
        l_r[r] = l_r[r] * corr + rs;
#pragma unroll
        for (int db = 0; db < 4; ++db) Oacc[db][r] *= corr;
      }

      // ---- stage P (bf16) to LDS in D-layout, swizzled ----
#pragma unroll
      for (int nb = 0; nb < 4; ++nb) {
#pragma unroll
        for (int r = 0; r < 4; ++r) {
          int prow = lg * 4 + r;
          int off = wave * 2048 + prow * 128 +
                    ((((nb * 16 + lr) * 2)) ^ ((prow & 7) << 4));
          *(u16*)((char*)sP + off) = f2bf(p[nb][r]);
        }
      }
      // ---- read P back as A-fragments ----
      bf16x8 pa[2];
#pragma unroll
      for (int kk = 0; kk < 2; ++kk) {
        int off = wave * 2048 + lr * 128 +
                  ((kk * 64 + lg * 16) ^ ((lr & 7) << 4));
        pa[kk] = *(const bf16x8*)((char*)sP + off);
      }
      // ---- PV: O[16 q][64 d] += P @ V ----
#pragma unroll
      for (int db = 0; db < 4; ++db) {
#pragma unroll
        for (int kk = 0; kk < 2; ++kk) {
          int vrow = db * 16 + lr;
          int off = vrow * 128 + ((kk * 64 + lg * 16) ^ ((vrow & 7) << 4));
          bf16x8 vb = *(const bf16x8*)((char*)sVt + off);
          Oacc[db] = MFMA16(pa[kk], vb, Oacc[db]);
        }
      }
    }
    __syncthreads();
  }

  // ---- epilogue: divide by l, store fp32 ----
  float invl[4];
#pragma unroll
  for (int r = 0; r < 4; ++r) invl[r] = 1.f / l_r[r];
#pragma unroll
  for (int db = 0; db < 4; ++db) {
#pragma unroll
    for (int r = 0; r < 4; ++r) {
      int q = q0 + wave * 16 + lg * 4 + r;
      Out[((size_t)bh * S_LEN + q) * D_HEAD + db * 16 + lr] =
          Oacc[db][r] * invl[r];
    }
  }
}

extern "C" void kernel_launch(void* const* d_in, const int* in_sizes, int n_in,
                              void* d_out, int out_size, void* d_ws,
                              size_t ws_size, hipStream_t stream) {
  const float* Hin = (const float*)d_in[0];
  const float* Hk = (const float*)d_in[1];
  const float* Hv = (const float*)d_in[2];
  // d_in[3] = mask (implemented analytically), d_in[5] = F_hidden (=64)
  const float* avAp = (const float*)d_in[4];
  float* Out = (float*)d_out;

  const size_t N = (size_t)NBH * S_LEN * D_HEAD;  // 4,194,304 elements
  u16* Qhi = (u16*)d_ws;
  u16* Qlo = Qhi + N;
  u16* Khi = Qlo + N;
  u16* Klo = Khi + N;
  u16* Vt = Klo + N;

  dim3 grid(S_LEN / 64, NBH);
  dim3 block(256);
  qproj_kernel<<<grid, block, 0, stream>>>(Hin, avAp, Qhi, Qlo);
  kvprep_kernel<<<grid, block, 0, stream>>>(Hk, Hv, Khi, Klo, Vt);
  attn_kernel<<<grid, block, 0, stream>>>(Qhi, Qlo, Khi, Klo, Vt, Out);
}

// Round 3
// 204.790 us; speedup vs baseline: 1.2144x; 1.2144x over previous
//
#include <hip/hip_runtime.h>

#define S_LEN 2048
#define NBH 32

typedef unsigned short u16;
typedef unsigned int u32;
typedef __attribute__((ext_vector_type(8))) short bf16x8;
typedef __attribute__((ext_vector_type(4))) float f32x4;

#define MFMA16(A, B, C) __builtin_amdgcn_mfma_f32_16x16x32_bf16(A, B, C, 0, 0, 0)

__device__ __forceinline__ u16 f2bf(float f) {
  u32 u = __builtin_bit_cast(u32, f);
  u += 0x7fffu + ((u >> 16) & 1u);
  return (u16)(u >> 16);
}
__device__ __forceinline__ float bf2f(u16 b) {
  u32 u = ((u32)b) << 16;
  return __builtin_bit_cast(float, u);
}
__device__ __forceinline__ u32 pack2(float a, float b) {
  return (u32)f2bf(a) | ((u32)f2bf(b) << 16);
}

// ---------- prep: K split to bf16 hi/lo; V -> V^T bf16 [bh][d][s] ----------
__global__ __launch_bounds__(256, 2) void kvprep_kernel(
    const float* __restrict__ Hk, const float* __restrict__ Hv,
    u16* __restrict__ Khi, u16* __restrict__ Klo, u16* __restrict__ Vt) {
  __shared__ float sT[64 * 68];
  const int bh = blockIdx.y, s0 = blockIdx.x * 64, tid = threadIdx.x;
  const size_t base = ((size_t)bh * S_LEN + s0) * 64;

#pragma unroll
  for (int i = 0; i < 2; ++i) {
    int c = tid + 256 * i;  // 512 chunks of 8 elements
    size_t off = base + (size_t)c * 8;
    float4 a = *(const float4*)(Hk + off);
    float4 b = *(const float4*)(Hk + off + 4);
    float xs[8] = {a.x, a.y, a.z, a.w, b.x, b.y, b.z, b.w};
    u32 wh[4], wl[4];
#pragma unroll
    for (int j = 0; j < 4; ++j) {
      u16 h0 = f2bf(xs[2 * j]), h1 = f2bf(xs[2 * j + 1]);
      wh[j] = (u32)h0 | ((u32)h1 << 16);
      wl[j] = (u32)f2bf(xs[2 * j] - bf2f(h0)) |
              ((u32)f2bf(xs[2 * j + 1] - bf2f(h1)) << 16);
    }
    *(uint4*)(Khi + off) = make_uint4(wh[0], wh[1], wh[2], wh[3]);
    *(uint4*)(Klo + off) = make_uint4(wl[0], wl[1], wl[2], wl[3]);
    float4 v0 = *(const float4*)(Hv + off);
    float4 v1 = *(const float4*)(Hv + off + 4);
    int row = c >> 3, col = (c & 7) * 8;
    *(float4*)(sT + row * 68 + col) = v0;
    *(float4*)(sT + row * 68 + col + 4) = v1;
  }
  __syncthreads();

#pragma unroll
  for (int i = 0; i < 2; ++i) {
    int c = tid + 256 * i;  // d = c>>3 (0..63), s8 = (c&7)*8
    int d = c >> 3, s8 = (c & 7) * 8;
    u32 w[4];
#pragma unroll
    for (int j = 0; j < 4; ++j)
      w[j] = pack2(sT[(s8 + 2 * j) * 68 + d], sT[(s8 + 2 * j + 1) * 68 + d]);
    *(uint4*)(Vt + ((size_t)bh * 64 + d) * S_LEN + s0 + s8) =
        make_uint4(w[0], w[1], w[2], w[3]);
  }
}

// ---------- fused: Q-projection prologue + causal flash attention ----------
// LDS carve (64 KB):
//   [    0,16384) sKhi double-buffer (2 x 8 KB)
//   [16384,32768) sKlo double-buffer
//   [32768,49152) sVt  double-buffer
//   [49152,65536) sP (4 KB per wave); aliased with avAp fp32 in prologue
__global__ __launch_bounds__(256, 2) void attn_kernel(
    const float* __restrict__ Hin, const float* __restrict__ avAp,
    const u16* __restrict__ Khi, const u16* __restrict__ Klo,
    const u16* __restrict__ Vt, float* __restrict__ Out) {
  __shared__ __align__(16) char smem[65536];

  const int bh = blockIdx.y;
  const int h = bh & 15;
  const int x = blockIdx.x;
  // complement pairing: block i and i+256 (same x, batch 0 vs 1) get qtiles
  // summing to 15 -> per-CU work balanced under round-robin dispatch
  const int qtile = ((bh >> 4) & 1) ? x : ((int)gridDim.x - 1 - x);
  const int q0 = qtile * 128;
  const int tid = threadIdx.x, wave = tid >> 6, lane = tid & 63;
  const int lr = lane & 15, lg = lane >> 4;
  const int nT = 2 * qtile + 2;

  // staging geometry (per thread: 2 chunks of 8 bf16)
  int srow[2], sc16[2], sdst[2];
#pragma unroll
  for (int i = 0; i < 2; ++i) {
    int c = tid + 256 * i;
    srow[i] = c >> 3;
    sc16[i] = c & 7;
    sdst[i] = srow[i] * 128 + ((sc16[i] * 16) ^ ((srow[i] & 7) << 4));
  }

  // ---- issue tile-0 K/V prefetch (latency hidden under Q' projection) ----
  bf16x8 rkh[2], rkl[2], rv[2];
#pragma unroll
  for (int i = 0; i < 2; ++i) {
    size_t ko = ((size_t)bh * S_LEN + srow[i]) * 64 + sc16[i] * 8;
    rkh[i] = *(const bf16x8*)(Khi + ko);
    rkl[i] = *(const bf16x8*)(Klo + ko);
    size_t vo = ((size_t)bh * 64 + srow[i]) * S_LEN + sc16[i] * 8;
    rv[i] = *(const bf16x8*)(Vt + vo);
  }

  // ---- stage avAp[h] (fp32, 16 KB) into sP region ----
  float* sA = (float*)(smem + 49152);
#pragma unroll
  for (int i = 0; i < 4; ++i) {
    int c = tid + 256 * i;
    *(float4*)(sA + c * 4) = *(const float4*)(avAp + (size_t)h * 4096 + c * 4);
  }
  __syncthreads();

  // ---- Hin A-fragments (split bf16), direct from global ----
  bf16x8 ahi[2][2], alo[2][2];
#pragma unroll
  for (int hf = 0; hf < 2; ++hf)
#pragma unroll
    for (int kk = 0; kk < 2; ++kk) {
      const float* src = Hin +
          ((size_t)bh * S_LEN + q0 + wave * 32 + hf * 16 + lr) * 64 +
          kk * 32 + lg * 8;
      float4 u = *(const float4*)src;
      float4 w = *(const float4*)(src + 4);
      float xs[8] = {u.x, u.y, u.z, u.w, w.x, w.y, w.z, w.w};
#pragma unroll
      for (int j = 0; j < 8; ++j) {
        u16 hh = f2bf(xs[j]);
        ahi[hf][kk][j] = (short)hh;
        alo[hf][kk][j] = (short)f2bf(xs[j] - bf2f(hh));
      }
    }

  // ---- avAp^T B-fragments (split bf16) from LDS ----
  bf16x8 bhi[4][2], blo[4][2];
#pragma unroll
  for (int nb = 0; nb < 4; ++nb)
#pragma unroll
    for (int kk = 0; kk < 2; ++kk) {
#pragma unroll
      for (int j = 0; j < 8; ++j) {
        float xv = sA[(kk * 32 + lg * 8 + j) * 64 + nb * 16 + lr];
        u16 hh = f2bf(xv);
        bhi[nb][kk][j] = (short)hh;
        blo[nb][kk][j] = (short)f2bf(xv - bf2f(hh));
      }
    }
  __syncthreads();  // everyone done reading sA before sP overwrites it

  // ---- Q' = Hin @ avAp (split MFMA, 48 per wave) ----
  f32x4 qa[2][4];
#pragma unroll
  for (int hf = 0; hf < 2; ++hf)
#pragma unroll
    for (int nb = 0; nb < 4; ++nb) qa[hf][nb] = (f32x4){0.f, 0.f, 0.f, 0.f};
#pragma unroll
  for (int hf = 0; hf < 2; ++hf)
#pragma unroll
    for (int nb = 0; nb < 4; ++nb)
#pragma unroll
      for (int kk = 0; kk < 2; ++kk) {
        qa[hf][nb] = MFMA16(ahi[hf][kk], bhi[nb][kk], qa[hf][nb]);
        qa[hf][nb] = MFMA16(alo[hf][kk], bhi[nb][kk], qa[hf][nb]);
        qa[hf][nb] = MFMA16(ahi[hf][kk], blo[nb][kk], qa[hf][nb]);
      }

  // ---- route Q' (pre-scaled by 1/sqrt(64)) to A-fragment layout via sP ----
  u16* sP = (u16*)(smem + 49152 + wave * 4096);
  bf16x8 qhi[2][2], qlo[2][2];
#pragma unroll
  for (int hf = 0; hf < 2; ++hf)
#pragma unroll
    for (int nb = 0; nb < 4; ++nb)
#pragma unroll
      for (int r = 0; r < 4; ++r) {
        int prow = hf * 16 + lg * 4 + r, col = nb * 16 + lr;
        float v = qa[hf][nb][r] * 0.125f;
        *(u16*)((char*)sP + prow * 128 + ((col * 2) ^ ((prow & 7) << 4))) =
            f2bf(v);
      }
  __syncthreads();
#pragma unroll
  for (int hf = 0; hf < 2; ++hf)
#pragma unroll
    for (int kk = 0; kk < 2; ++kk)
      qhi[hf][kk] = *(const bf16x8*)((char*)sP + (hf * 16 + lr) * 128 +
                                     ((kk * 64 + lg * 16) ^ ((lr & 7) << 4)));
  __syncthreads();
#pragma unroll
  for (int hf = 0; hf < 2; ++hf)
#pragma unroll
    for (int nb = 0; nb < 4; ++nb)
#pragma unroll
      for (int r = 0; r < 4; ++r) {
        int prow = hf * 16 + lg * 4 + r, col = nb * 16 + lr;
        float v = qa[hf][nb][r] * 0.125f;
        u16 hh = f2bf(v);
        *(u16*)((char*)sP + prow * 128 + ((col * 2) ^ ((prow & 7) << 4))) =
            f2bf(v - bf2f(hh));
      }
  __syncthreads();
#pragma unroll
  for (int hf = 0; hf < 2; ++hf)
#pragma unroll
    for (int kk = 0; kk < 2; ++kk)
      qlo[hf][kk] = *(const bf16x8*)((char*)sP + (hf * 16 + lr) * 128 +
                                     ((kk * 64 + lg * 16) ^ ((lr & 7) << 4)));
  __syncthreads();

  // ---- write tile-0 staging regs -> LDS buf 0 ----
  int buf = 0;
#pragma unroll
  for (int i = 0; i < 2; ++i) {
    *(bf16x8*)(smem + sdst[i]) = rkh[i];
    *(bf16x8*)(smem + 16384 + sdst[i]) = rkl[i];
    *(bf16x8*)(smem + 32768 + sdst[i]) = rv[i];
  }
  __syncthreads();

  f32x4 Oacc[2][4];
#pragma unroll
  for (int hf = 0; hf < 2; ++hf)
#pragma unroll
    for (int db = 0; db < 4; ++db) Oacc[hf][db] = (f32x4){0.f, 0.f, 0.f, 0.f};
  float m_r[2][4], l_r[2][4];
#pragma unroll
  for (int hf = 0; hf < 2; ++hf)
#pragma unroll
    for (int r = 0; r < 4; ++r) {
      m_r[hf][r] = -3.0e38f;
      l_r[hf][r] = 0.f;
    }

  // ---- main loop: one barrier per KV tile, prefetch hidden under compute ----
  for (int t = 0; t < nT; ++t) {
    const int kv0 = t * 64;
    const bool pf = (t + 1 < nT);
    if (pf) {
      const int kvn = kv0 + 64;
#pragma unroll
      for (int i = 0; i < 2; ++i) {
        size_t ko = ((size_t)bh * S_LEN + kvn + srow[i]) * 64 + sc16[i] * 8;
        rkh[i] = *(const bf16x8*)(Khi + ko);
        rkl[i] = *(const bf16x8*)(Klo + ko);
        size_t vo = ((size_t)bh * 64 + srow[i]) * S_LEN + kvn + sc16[i] * 8;
        rv[i] = *(const bf16x8*)(Vt + vo);
      }
    }

    const int bK = buf * 8192;
    if (kv0 <= q0 + wave * 32 + 31) {  // wave-uniform causal activity
      // ---- QK^T (split, 48 MFMA/wave) ----
      f32x4 sacc[2][4];
#pragma unroll
      for (int hf = 0; hf < 2; ++hf)
#pragma unroll
        for (int nb = 0; nb < 4; ++nb) sacc[hf][nb] = (f32x4){0.f, 0.f, 0.f, 0.f};
#pragma unroll
      for (int nb = 0; nb < 4; ++nb) {
        int krow = nb * 16 + lr;
#pragma unroll
        for (int kk = 0; kk < 2; ++kk) {
          int off = krow * 128 + ((kk * 64 + lg * 16) ^ ((krow & 7) << 4));
          bf16x8 kh = *(const bf16x8*)(smem + bK + off);
          bf16x8 kl = *(const bf16x8*)(smem + 16384 + bK + off);
#pragma unroll
          for (int hf = 0; hf < 2; ++hf) {
            sacc[hf][nb] = MFMA16(qhi[hf][kk], kh, sacc[hf][nb]);
            sacc[hf][nb] = MFMA16(qlo[hf][kk], kh, sacc[hf][nb]);
            sacc[hf][nb] = MFMA16(qhi[hf][kk], kl, sacc[hf][nb]);
          }
        }
      }

      // ---- online softmax (mask only near the diagonal) ----
      const bool needMask = (kv0 + 63 > q0);
#pragma unroll
      for (int hf = 0; hf < 2; ++hf) {
        float tmax[4] = {-3.0e38f, -3.0e38f, -3.0e38f, -3.0e38f};
        if (needMask) {
#pragma unroll
          for (int nb = 0; nb < 4; ++nb) {
            int kvg = kv0 + nb * 16 + lr;
#pragma unroll
            for (int r = 0; r < 4; ++r) {
              float v = sacc[hf][nb][r];
              int qg = q0 + wave * 32 + hf * 16 + lg * 4 + r;
              if (kvg > qg) v = -1.0e30f;
              sacc[hf][nb][r] = v;
              tmax[r] = fmaxf(tmax[r], v);
            }
          }
        } else {
#pragma unroll
          for (int nb = 0; nb < 4; ++nb)
#pragma unroll
            for (int r = 0; r < 4; ++r) tmax[r] = fmaxf(tmax[r], sacc[hf][nb][r]);
        }
#pragma unroll
        for (int r = 0; r < 4; ++r) {
          float tm = tmax[r];
          tm = fmaxf(tm, __shfl_xor(tm, 1));
          tm = fmaxf(tm, __shfl_xor(tm, 2));
          tm = fmaxf(tm, __shfl_xor(tm, 4));
          tm = fmaxf(tm, __shfl_xor(tm, 8));
          float mo = m_r[hf][r], mn = fmaxf(mo, tm);
          float corr = __expf(mo - mn);
          m_r[hf][r] = mn;
          float rs = 0.f;
#pragma unroll
          for (int nb = 0; nb < 4; ++nb) {
            float e = __expf(sacc[hf][nb][r] - mn);
            sacc[hf][nb][r] = e;
            rs += e;
          }
          rs += __shfl_xor(rs, 1);
          rs += __shfl_xor(rs, 2);
          rs += __shfl_xor(rs, 4);
          rs += __shfl_xor(rs, 8);
          l_r[hf][r] = l_r[hf][r] * corr + rs;
#pragma unroll
          for (int db = 0; db < 4; ++db) Oacc[hf][db][r] *= corr;
        }
      }

      // ---- P -> LDS (D-layout) -> A-fragments ----
#pragma unroll
      for (int hf = 0; hf < 2; ++hf)
#pragma unroll
        for (int nb = 0; nb < 4; ++nb)
#pragma unroll
          for (int r = 0; r < 4; ++r) {
            int prow = hf * 16 + lg * 4 + r, col = nb * 16 + lr;
            *(u16*)((char*)sP + prow * 128 +
                    ((col * 2) ^ ((prow & 7) << 4))) = f2bf(sacc[hf][nb][r]);
          }
      bf16x8 pa[2][2];
#pragma unroll
      for (int hf = 0; hf < 2; ++hf)
#pragma unroll
        for (int kk = 0; kk < 2; ++kk)
          pa[hf][kk] =
              *(const bf16x8*)((char*)sP + (hf * 16 + lr) * 128 +
                               ((kk * 64 + lg * 16) ^ ((lr & 7) << 4)));

      // ---- PV (16 MFMA/wave), V-fragments shared across halves ----
#pragma unroll
      for (int db = 0; db < 4; ++db) {
        int vrow = db * 16 + lr;
#pragma unroll
        for (int kk = 0; kk < 2; ++kk) {
          int off = vrow * 128 + ((kk * 64 + lg * 16) ^ ((vrow & 7) << 4));
          bf16x8 vb = *(const bf16x8*)(smem + 32768 + bK + off);
#pragma unroll
          for (int hf = 0; hf < 2; ++hf)
            Oacc[hf][db] = MFMA16(pa[hf][kk], vb, Oacc[hf][db]);
        }
      }
    }

    // ---- write prefetched tile to the other buffer; single barrier ----
    if (pf) {
      const int bN = (buf ^ 1) * 8192;
#pragma unroll
      for (int i = 0; i < 2; ++i) {
        *(bf16x8*)(smem + bN + sdst[i]) = rkh[i];
        *(bf16x8*)(smem + 16384 + bN + sdst[i]) = rkl[i];
        *(bf16x8*)(smem + 32768 + bN + sdst[i]) = rv[i];
      }
    }
    __syncthreads();
    buf ^= 1;
  }

  // ---- epilogue ----
#pragma unroll
  for (int hf = 0; hf < 2; ++hf) {
    float invl[4];
#pragma unroll
    for (int r = 0; r < 4; ++r) invl[r] = 1.f / l_r[hf][r];
#pragma unroll
    for (int db = 0; db < 4; ++db)
#pragma unroll
      for (int r = 0; r < 4; ++r) {
        int q = q0 + wave * 32 + hf * 16 + lg * 4 + r;
        Out[((size_t)bh * S_LEN + q) * 64 + db * 16 + lr] =
            Oacc[hf][db][r] * invl[r];
      }
  }
}

extern "C" void kernel_launch(void* const* d_in, const int* in_sizes, int n_in,
                              void* d_out, int out_size, void* d_ws,
                              size_t ws_size, hipStream_t stream) {
  const float* Hin = (const float*)d_in[0];
  const float* Hk = (const float*)d_in[1];
  const float* Hv = (const float*)d_in[2];
  // d_in[3] = mask (analytic), d_in[5] = F_hidden (=64)
  const float* avAp = (const float*)d_in[4];
  float* Out = (float*)d_out;

  const size_t N = (size_t)NBH * S_LEN * 64;  // 4,194,304 elements
  u16* Khi = (u16*)d_ws;
  u16* Klo = Khi + N;
  u16* Vt = Klo + N;

  dim3 block(256);
  kvprep_kernel<<<dim3(S_LEN / 64, NBH), block, 0, stream>>>(Hk, Hv, Khi, Klo,
                                                             Vt);
  attn_kernel<<<dim3(S_LEN / 128, NBH), block, 0, stream>>>(Hin, avAp, Khi,
                                                            Klo, Vt, Out);
}

// Round 5
// 170.885 us; speedup vs baseline: 1.4553x; 1.1984x over previous
//
#include <hip/hip_runtime.h>

#define S_LEN 2048
#define NBH 32

typedef unsigned short u16;
typedef unsigned int u32;
typedef __attribute__((ext_vector_type(8))) short bf16x8;
typedef __attribute__((ext_vector_type(4))) float f32x4;

#define MFMA16(A, B, C) __builtin_amdgcn_mfma_f32_16x16x32_bf16(A, B, C, 0, 0, 0)

__device__ __forceinline__ u16 f2bf(float f) {
  u32 u = __builtin_bit_cast(u32, f);
  u += 0x7fffu + ((u >> 16) & 1u);
  return (u16)(u >> 16);
}
__device__ __forceinline__ float bf2f(u16 b) {
  u32 u = ((u32)b) << 16;
  return __builtin_bit_cast(float, u);
}
__device__ __forceinline__ u32 pack2(float a, float b) {
  return (u32)f2bf(a) | ((u32)f2bf(b) << 16);
}

// ---------- prep: V -> V^T bf16 [bh][d][s], bank-clean transpose ----------
__global__ __launch_bounds__(256, 2) void vtprep_kernel(
    const float* __restrict__ Hv, u16* __restrict__ Vt) {
  __shared__ u16 sT[64 * 66];  // [s][d], stride 66 elems (132B): reads ~2-way
  const int bh = blockIdx.y, s0 = blockIdx.x * 64, tid = threadIdx.x;
  const size_t base = ((size_t)bh * S_LEN + s0) * 64;

#pragma unroll
  for (int i = 0; i < 2; ++i) {
    int c = tid + 256 * i;  // 512 chunks of 8 floats
    int row = c >> 3, col8 = (c & 7) * 8;
    const float* src = Hv + base + (size_t)row * 64 + col8;
    float4 a = *(const float4*)src;
    float4 b = *(const float4*)(src + 4);
    u16* dst = sT + row * 66 + col8;
    // b32 writes (132B row stride is 4B-aligned only)
    *(u32*)(dst + 0) = pack2(a.x, a.y);
    *(u32*)(dst + 2) = pack2(a.z, a.w);
    *(u32*)(dst + 4) = pack2(b.x, b.y);
    *(u32*)(dst + 6) = pack2(b.z, b.w);
  }
  __syncthreads();

#pragma unroll
  for (int i = 0; i < 2; ++i) {
    int c = tid + 256 * i;  // d = c>>3 (0..63), s8 = (c&7)*8
    int d = c >> 3, s8 = (c & 7) * 8;
    u16 tmp[8];
#pragma unroll
    for (int j = 0; j < 8; ++j) tmp[j] = sT[(s8 + j) * 66 + d];
    *(uint4*)(Vt + ((size_t)bh * 64 + d) * S_LEN + s0 + s8) = *(uint4*)tmp;
  }
}

// ---------- fused: Q-projection prologue + causal flash attention ----------
// 8 waves x 16 q-rows (Q-tile 128). Swapped-operand MFMAs: lane owns q=lr.
// LDS (64 KB): sKhi dbuf [0,16K) | sKlo dbuf [16K,32K) | sVt dbuf [32K,48K)
//              sP [48K,64K) 2KB/wave (aliased with avAp fp32 in prologue)
__global__ __launch_bounds__(512, 4) void attn_kernel(
    const float* __restrict__ Hin, const float* __restrict__ avAp,
    const float* __restrict__ Hk, const u16* __restrict__ Vt,
    float* __restrict__ Out) {
  __shared__ __align__(16) char smem[65536];

  const int bh = blockIdx.y;
  const int h = bh & 15;
  const int x = blockIdx.x;
  // complement pairing for load balance across CUs
  const int qtile = ((bh >> 4) & 1) ? x : (15 - x);
  const int q0 = qtile * 128;
  const int tid = threadIdx.x, wave = tid >> 6, lane = tid & 63;
  const int lr = lane & 15, lg = lane >> 4;
  const int qrow = q0 + wave * 16 + lr;  // this lane's q-row (owned)
  const int nT = 2 * qtile + 2;

  // staging geometry: one 8-elem chunk per thread (64 rows x 8 chunks)
  const int srow = tid >> 3, sc16 = tid & 7;
  const int sdst = srow * 128 + ((sc16 * 16) ^ ((srow & 7) << 4));
  const float* kgp = Hk + ((size_t)bh * S_LEN + srow) * 64 + sc16 * 8;
  const u16* vgp = Vt + ((size_t)bh * 64 + srow) * S_LEN + sc16 * 8;

  // ---- issue tile-0 loads (hidden under Q' projection) ----
  float4 kaP = *(const float4*)(kgp);
  float4 kbP = *(const float4*)(kgp + 4);
  bf16x8 rvP = *(const bf16x8*)(vgp);

  // ---- stage avAp[h] fp32 into the sP region ----
  float* sA = (float*)(smem + 49152);
#pragma unroll
  for (int i = 0; i < 2; ++i) {
    int c = tid + 512 * i;  // float4 chunks 0..1023
    *(float4*)(sA + c * 4) = *(const float4*)(avAp + (size_t)h * 4096 + c * 4);
  }

  // ---- Hin fragments (split bf16) straight from global ----
  bf16x8 ahi[2], alo[2];
#pragma unroll
  for (int kk = 0; kk < 2; ++kk) {
    const float* src =
        Hin + ((size_t)bh * S_LEN + qrow) * 64 + kk * 32 + lg * 8;
    float4 u = *(const float4*)src;
    float4 w = *(const float4*)(src + 4);
    float xs[8] = {u.x, u.y, u.z, u.w, w.x, w.y, w.z, w.w};
#pragma unroll
    for (int j = 0; j < 8; ++j) {
      u16 hh = f2bf(xs[j]);
      ahi[kk][j] = (short)hh;
      alo[kk][j] = (short)f2bf(xs[j] - bf2f(hh));
    }
  }
  __syncthreads();

  // ---- Q'^T = avAp^T @ Hin^T (swapped; 24 split MFMAs) ----
  f32x4 qa[4];
#pragma unroll
  for (int nb = 0; nb < 4; ++nb) qa[nb] = (f32x4){0.f, 0.f, 0.f, 0.f};
#pragma unroll
  for (int kk = 0; kk < 2; ++kk) {
    bf16x8 bhiK[4], bloK[4];
#pragma unroll
    for (int nb = 0; nb < 4; ++nb) {
#pragma unroll
      for (int j = 0; j < 8; ++j) {
        float xv = sA[(kk * 32 + lg * 8 + j) * 64 + nb * 16 + lr];
        u16 hh = f2bf(xv);
        bhiK[nb][j] = (short)hh;
        bloK[nb][j] = (short)f2bf(xv - bf2f(hh));
      }
    }
#pragma unroll
    for (int nb = 0; nb < 4; ++nb) {
      qa[nb] = MFMA16(bhiK[nb], ahi[kk], qa[nb]);
      qa[nb] = MFMA16(bloK[nb], ahi[kk], qa[nb]);
      qa[nb] = MFMA16(bhiK[nb], alo[kk], qa[nb]);
    }
  }
  __syncthreads();  // sA dead; sP region now usable

  // ---- route Q' to B-fragments via per-wave sP (scale folds 1/8 and 1/ln2) ----
  const float QSCALE = 0.125f * 1.44269504088896f;
  char* sPw = smem + 49152 + wave * 2048;
  bf16x8 qhi[2], qlo[2];
#pragma unroll
  for (int nb = 0; nb < 4; ++nb)
#pragma unroll
    for (int i = 0; i < 2; ++i) {
      int e = nb * 16 + lg * 4 + 2 * i;
      *(u32*)(sPw + lr * 128 + ((e * 2) ^ ((lr & 7) << 4))) =
          pack2(qa[nb][2 * i] * QSCALE, qa[nb][2 * i + 1] * QSCALE);
    }
#pragma unroll
  for (int kk = 0; kk < 2; ++kk)
    qhi[kk] = *(const bf16x8*)(sPw + lr * 128 +
                               ((kk * 64 + lg * 16) ^ ((lr & 7) << 4)));
#pragma unroll
  for (int nb = 0; nb < 4; ++nb)
#pragma unroll
    for (int i = 0; i < 2; ++i) {
      int e = nb * 16 + lg * 4 + 2 * i;
      float v0 = qa[nb][2 * i] * QSCALE, v1 = qa[nb][2 * i + 1] * QSCALE;
      *(u32*)(sPw + lr * 128 + ((e * 2) ^ ((lr & 7) << 4))) =
          pack2(v0 - bf2f(f2bf(v0)), v1 - bf2f(f2bf(v1)));
    }
#pragma unroll
  for (int kk = 0; kk < 2; ++kk)
    qlo[kk] = *(const bf16x8*)(sPw + lr * 128 +
                               ((kk * 64 + lg * 16) ^ ((lr & 7) << 4)));

  // ---- write tile-0 staging (K converted fp32 -> bf16 hi/lo here) ----
  int buf = 0;
  {
    float xs[8] = {kaP.x, kaP.y, kaP.z, kaP.w, kbP.x, kbP.y, kbP.z, kbP.w};
    bf16x8 khi8, klo8;
#pragma unroll
    for (int j = 0; j < 8; ++j) {
      u16 hh = f2bf(xs[j]);
      khi8[j] = (short)hh;
      klo8[j] = (short)f2bf(xs[j] - bf2f(hh));
    }
    *(bf16x8*)(smem + sdst) = khi8;
    *(bf16x8*)(smem + 16384 + sdst) = klo8;
    *(bf16x8*)(smem + 32768 + sdst) = rvP;
  }
  __syncthreads();

  f32x4 Oacc[4];
#pragma unroll
  for (int db = 0; db < 4; ++db) Oacc[db] = (f32x4){0.f, 0.f, 0.f, 0.f};
  float m_r = -3.0e38f, l_r = 0.f;

  // ---- main loop: one barrier per KV tile ----
  for (int t = 0; t < nT; ++t) {
    const int kv0 = t * 64;
    const bool pf = (t + 1 < nT);
    if (pf) {
      const size_t ko = (size_t)(kv0 + 64) * 64;
      kaP = *(const float4*)(kgp + ko);
      kbP = *(const float4*)(kgp + ko + 4);
      rvP = *(const bf16x8*)(vgp + kv0 + 64);
    }

    const int bK = buf * 8192;
    if (kv0 <= q0 + wave * 16 + 15) {  // wave-uniform causal activity
      // ---- QK^T swapped: sacc[nb][r] = S[kv0+nb*16+lg*4+r][qrow] ----
      f32x4 sacc[4];
#pragma unroll
      for (int nb = 0; nb < 4; ++nb) sacc[nb] = (f32x4){0.f, 0.f, 0.f, 0.f};
#pragma unroll
      for (int nb = 0; nb < 4; ++nb) {
        int krow = nb * 16 + lr;
#pragma unroll
        for (int kk = 0; kk < 2; ++kk) {
          int off = krow * 128 + ((kk * 64 + lg * 16) ^ ((krow & 7) << 4));
          bf16x8 kh = *(const bf16x8*)(smem + bK + off);
          bf16x8 kl = *(const bf16x8*)(smem + 16384 + bK + off);
          sacc[nb] = MFMA16(kh, qhi[kk], sacc[nb]);
          sacc[nb] = MFMA16(kl, qhi[kk], sacc[nb]);
          sacc[nb] = MFMA16(kh, qlo[kk], sacc[nb]);
        }
      }

      // ---- causal mask (boundary tiles only; wave-uniform branch) ----
      if (kv0 + 63 > q0 + wave * 16) {
#pragma unroll
        for (int nb = 0; nb < 4; ++nb)
#pragma unroll
          for (int r = 0; r < 4; ++r)
            if (kv0 + nb * 16 + lg * 4 + r > qrow) sacc[nb][r] = -1.0e30f;
      }

      // ---- per-lane online softmax (log2 domain), 2 shuffles per reduce ----
      float tmax = sacc[0][0];
#pragma unroll
      for (int nb = 0; nb < 4; ++nb)
#pragma unroll
        for (int r = 0; r < 4; ++r) tmax = fmaxf(tmax, sacc[nb][r]);
      tmax = fmaxf(tmax, __shfl_xor(tmax, 16));
      tmax = fmaxf(tmax, __shfl_xor(tmax, 32));
      float mn = fmaxf(m_r, tmax);
      float corr = exp2f(m_r - mn);
      m_r = mn;
      float rs = 0.f;
#pragma unroll
      for (int nb = 0; nb < 4; ++nb)
#pragma unroll
        for (int r = 0; r < 4; ++r) {
          float e = exp2f(sacc[nb][r] - mn);
          sacc[nb][r] = e;
          rs += e;
        }
      rs += __shfl_xor(rs, 16);
      rs += __shfl_xor(rs, 32);
      l_r = l_r * corr + rs;
#pragma unroll
      for (int db = 0; db < 4; ++db) Oacc[db] *= corr;

      // ---- P -> sP (8 packed b32 writes) -> B-fragments ----
#pragma unroll
      for (int nb = 0; nb < 4; ++nb)
#pragma unroll
        for (int i = 0; i < 2; ++i) {
          int kv = nb * 16 + lg * 4 + 2 * i;
          *(u32*)(sPw + lr * 128 + ((kv * 2) ^ ((lr & 7) << 4))) =
              pack2(sacc[nb][2 * i], sacc[nb][2 * i + 1]);
        }
      bf16x8 pa[2];
#pragma unroll
      for (int kk = 0; kk < 2; ++kk)
        pa[kk] = *(const bf16x8*)(sPw + lr * 128 +
                                  ((kk * 64 + lg * 16) ^ ((lr & 7) << 4)));

      // ---- PV swapped: Oacc[db][r] = O[qrow][db*16+lg*4+r] ----
#pragma unroll
      for (int db = 0; db < 4; ++db) {
        int vrow = db * 16 + lr;
#pragma unroll
        for (int kk = 0; kk < 2; ++kk) {
          int off = vrow * 128 + ((kk * 64 + lg * 16) ^ ((vrow & 7) << 4));
          bf16x8 vb = *(const bf16x8*)(smem + 32768 + bK + off);
          Oacc[db] = MFMA16(vb, pa[kk], Oacc[db]);
        }
      }
    }

    // ---- write prefetched tile to the other buffer; single barrier ----
    if (pf) {
      const int bN = (buf ^ 1) * 8192;
      float xs[8] = {kaP.x, kaP.y, kaP.z, kaP.w, kbP.x, kbP.y, kbP.z, kbP.w};
      bf16x8 khi8, klo8;
#pragma unroll
      for (int j = 0; j < 8; ++j) {
        u16 hh = f2bf(xs[j]);
        khi8[j] = (short)hh;
        klo8[j] = (short)f2bf(xs[j] - bf2f(hh));
      }
      *(bf16x8*)(smem + bN + sdst) = khi8;
      *(bf16x8*)(smem + 16384 + bN + sdst) = klo8;
      *(bf16x8*)(smem + 32768 + bN + sdst) = rvP;
    }
    __syncthreads();
    buf ^= 1;
  }

  // ---- epilogue: coalesced float4 stores ----
  float invl = 1.0f / l_r;
  float* orow = Out + ((size_t)bh * S_LEN + qrow) * 64;
#pragma unroll
  for (int db = 0; db < 4; ++db) {
    float4 o = make_float4(Oacc[db][0] * invl, Oacc[db][1] * invl,
                           Oacc[db][2] * invl, Oacc[db][3] * invl);
    *(float4*)(orow + db * 16 + lg * 4) = o;
  }
}

extern "C" void kernel_launch(void* const* d_in, const int* in_sizes, int n_in,
                              void* d_out, int out_size, void* d_ws,
                              size_t ws_size, hipStream_t stream) {
  const float* Hin = (const float*)d_in[0];
  const float* Hk = (const float*)d_in[1];
  const float* Hv = (const float*)d_in[2];
  // d_in[3] = mask (analytic), d_in[5] = F_hidden (=64)
  const float* avAp = (const float*)d_in[4];
  float* Out = (float*)d_out;

  u16* Vt = (u16*)d_ws;  // 32*2048*64 bf16 = 8 MB

  vtprep_kernel<<<dim3(S_LEN / 64, NBH), dim3(256), 0, stream>>>(Hv, Vt);
  attn_kernel<<<dim3(S_LEN / 128, NBH), dim3(512), 0, stream>>>(Hin, avAp, Hk,
                                                                Vt, Out);
}

// Round 6
// 161.752 us; speedup vs baseline: 1.5375x; 1.0565x over previous
//
#include <hip/hip_runtime.h>

#define S_LEN 2048
#define NBH 32

typedef unsigned short u16;
typedef unsigned int u32;
typedef __attribute__((ext_vector_type(8))) short bf16x8;
typedef __attribute__((ext_vector_type(4))) float f32x4;

#define MFMA16(A, B, C) __builtin_amdgcn_mfma_f32_16x16x32_bf16(A, B, C, 0, 0, 0)

__device__ __forceinline__ u16 f2bf(float f) {
  u32 u = __builtin_bit_cast(u32, f);
  u += 0x7fffu + ((u >> 16) & 1u);
  return (u16)(u >> 16);
}
__device__ __forceinline__ float bf2f(u16 b) {
  u32 u = ((u32)b) << 16;
  return __builtin_bit_cast(float, u);
}
__device__ __forceinline__ u32 pack2(float a, float b) {
  return (u32)f2bf(a) | ((u32)f2bf(b) << 16);
}
__device__ __forceinline__ u32 cvtpk(float a, float b) {
  u32 r;
  asm("v_cvt_pk_bf16_f32 %0, %1, %2" : "=v"(r) : "v"(a), "v"(b));
  return r;
}
__device__ __forceinline__ void gld16(const void* g, void* l) {
  __builtin_amdgcn_global_load_lds(
      (const __attribute__((address_space(1))) void*)g,
      (__attribute__((address_space(3))) void*)l, 16, 0, 0);
}

// ---------- prep: K -> bf16 hi/lo blobs, V -> V^T blobs ----------
// Blob layout per (bh, 64-kv tile): 512 chunks of 16B, chunk o holds
// row = o>>3, source 8-elem chunk ci = (o&7) ^ (row&7)  (pre-swizzled so a
// linear global_load_lds deposit matches attn's XOR-swizzled LDS reads).
__global__ __launch_bounds__(256) void prep_kernel(
    const float* __restrict__ Hk, const float* __restrict__ Hv,
    u16* __restrict__ Khb, u16* __restrict__ Klb, u16* __restrict__ Vtb) {
  __shared__ u16 sT[64 * 66];  // V tile [s][d], stride 66
  const int bh = blockIdx.y, t = blockIdx.x, tid = threadIdx.x;
  const size_t base = ((size_t)bh * S_LEN + t * 64) * 64;
  const size_t bb = ((size_t)bh * 32 + t) * 4096;  // u16 elems per blob tile

#pragma unroll
  for (int i = 0; i < 2; ++i) {
    int c = tid + 256 * i;  // 0..511
    int row = c >> 3, ci = c & 7;
    const float* ks = Hk + base + (size_t)row * 64 + ci * 8;
    float4 a = *(const float4*)ks, b = *(const float4*)(ks + 4);
    float xs[8] = {a.x, a.y, a.z, a.w, b.x, b.y, b.z, b.w};
    u16 hi[8], lo[8];
#pragma unroll
    for (int j = 0; j < 8; ++j) {
      hi[j] = f2bf(xs[j]);
      lo[j] = f2bf(xs[j] - bf2f(hi[j]));
    }
    int o = (c & ~7) | (ci ^ (row & 7));
    *(uint4*)(Khb + bb + o * 8) = *(uint4*)hi;
    *(uint4*)(Klb + bb + o * 8) = *(uint4*)lo;

    const float* vs = Hv + base + (size_t)row * 64 + ci * 8;
    float4 va = *(const float4*)vs, vb = *(const float4*)(vs + 4);
    u16* dst = sT + row * 66 + ci * 8;
    *(u32*)(dst + 0) = pack2(va.x, va.y);
    *(u32*)(dst + 2) = pack2(va.z, va.w);
    *(u32*)(dst + 4) = pack2(vb.x, vb.y);
    *(u32*)(dst + 6) = pack2(vb.z, vb.w);
  }
  __syncthreads();

#pragma unroll
  for (int i = 0; i < 2; ++i) {
    int o = tid + 256 * i;  // output chunk (d-row major, pre-swizzled s-chunk)
    int d = o >> 3, s8 = ((o & 7) ^ (d & 7)) * 8;
    u16 tmp[8];
#pragma unroll
    for (int j = 0; j < 8; ++j) tmp[j] = sT[(s8 + j) * 66 + d];
    *(uint4*)(Vtb + bb + o * 8) = *(uint4*)tmp;
  }
}

// ---------- fused: Q-projection prologue + causal flash attention ----------
// 8 waves x 16 q-rows. Staging = 3x global_load_lds dwordx4/thread/tile.
// LDS (64 KB): Khi dbuf [0,16K) | Klo dbuf [16K,32K) | Vt dbuf [32K,48K)
//              sP [48K,64K) 2KB/wave (aliased with swizzled avAp in prologue)
__global__ __launch_bounds__(512, 4) void attn_kernel(
    const float* __restrict__ Hin, const float* __restrict__ avAp,
    const u16* __restrict__ Khb, const u16* __restrict__ Klb,
    const u16* __restrict__ Vtb, float* __restrict__ Out) {
  __shared__ __align__(16) char smem[65536];

  const int bh = blockIdx.y;
  const int h = bh & 15;
  const int x = blockIdx.x;
  const int qtile = ((bh >> 4) & 1) ? x : (15 - x);  // complement pairing
  const int q0 = qtile * 128;
  const int tid = threadIdx.x, wave = tid >> 6, lane = tid & 63;
  const int lr = lane & 15, lg = lane >> 4;
  const int qrow = q0 + wave * 16 + lr;
  const int nT = 2 * qtile + 2;

#define STAGE(tt, bN)                                              \
  {                                                                \
    const size_t go = (((size_t)bh * 32 + (tt)) * 512 + tid) * 16; \
    char* lw = smem + (bN) + wave * 1024;                          \
    gld16((const char*)Khb + go, lw);                              \
    gld16((const char*)Klb + go, lw + 16384);                      \
    gld16((const char*)Vtb + go, lw + 32768);                      \
  }

  // ---- issue tile-0 blob loads (complete at first barrier) ----
  STAGE(0, 0);

  // ---- stage avAp[h] into bank-swizzled sA (prologue-only region) ----
  char* sAB = smem + 49152;
#pragma unroll
  for (int i = 0; i < 2; ++i) {
    int c = tid + 512 * i;  // 1024 float4 chunks
    int d = c >> 4, c4 = c & 15;
    int key = (((d >> 3) & 1) << 4) | (((d >> 4) & 1) << 6);
    *(float4*)(sAB + d * 256 + ((c4 * 16) ^ key)) =
        *(const float4*)(avAp + (size_t)h * 4096 + c * 4);
  }

  // ---- Hin fragments (split bf16) straight from global ----
  bf16x8 ahi[2], alo[2];
#pragma unroll
  for (int kk = 0; kk < 2; ++kk) {
    const float* src =
        Hin + ((size_t)bh * S_LEN + qrow) * 64 + kk * 32 + lg * 8;
    float4 u = *(const float4*)src;
    float4 w = *(const float4*)(src + 4);
    float xs[8] = {u.x, u.y, u.z, u.w, w.x, w.y, w.z, w.w};
#pragma unroll
    for (int j = 0; j < 8; ++j) {
      u16 hh = f2bf(xs[j]);
      ahi[kk][j] = (short)hh;
      alo[kk][j] = (short)f2bf(xs[j] - bf2f(hh));
    }
  }
  __syncthreads();  // sA visible; tile-0 blobs drained into buf0

  // ---- Q'^T = avAp^T @ Hin^T (swapped; 24 split MFMAs) ----
  const int keyA = ((lg & 1) << 4) | ((lg >> 1) << 6);
  f32x4 qa[4];
#pragma unroll
  for (int nb = 0; nb < 4; ++nb) qa[nb] = (f32x4){0.f, 0.f, 0.f, 0.f};
#pragma unroll
  for (int kk = 0; kk < 2; ++kk) {
    bf16x8 bhiK[4], bloK[4];
#pragma unroll
    for (int nb = 0; nb < 4; ++nb) {
#pragma unroll
      for (int j = 0; j < 8; ++j) {
        float xv = *(const float*)(sAB + (kk * 32 + lg * 8 + j) * 256 +
                                   (((nb * 16 + lr) * 4) ^ keyA));
        u16 hh = f2bf(xv);
        bhiK[nb][j] = (short)hh;
        bloK[nb][j] = (short)f2bf(xv - bf2f(hh));
      }
    }
#pragma unroll
    for (int nb = 0; nb < 4; ++nb) {
      qa[nb] = MFMA16(bhiK[nb], ahi[kk], qa[nb]);
      qa[nb] = MFMA16(bloK[nb], ahi[kk], qa[nb]);
      qa[nb] = MFMA16(bhiK[nb], alo[kk], qa[nb]);
    }
  }
  __syncthreads();  // all waves done with sA; sP region now usable

  // ---- route Q' to B-fragments via per-wave sP (scale: 1/8 and 1/ln2) ----
  const float QSCALE = 0.125f * 1.44269504088896f;
  char* sPw = smem + 49152 + wave * 2048;
  bf16x8 qhi[2], qlo[2];
#pragma unroll
  for (int nb = 0; nb < 4; ++nb) {
    uint2 w;
    w.x = pack2(qa[nb][0] * QSCALE, qa[nb][1] * QSCALE);
    w.y = pack2(qa[nb][2] * QSCALE, qa[nb][3] * QSCALE);
    *(uint2*)(sPw + lr * 128 + ((nb * 32 + lg * 8) ^ ((lr & 7) << 4))) = w;
  }
#pragma unroll
  for (int kk = 0; kk < 2; ++kk)
    qhi[kk] = *(const bf16x8*)(sPw + lr * 128 +
                               ((kk * 64 + lg * 16) ^ ((lr & 7) << 4)));
#pragma unroll
  for (int nb = 0; nb < 4; ++nb) {
    float v[4];
#pragma unroll
    for (int r = 0; r < 4; ++r) {
      float s = qa[nb][r] * QSCALE;
      v[r] = s - bf2f(f2bf(s));
    }
    uint2 w;
    w.x = pack2(v[0], v[1]);
    w.y = pack2(v[2], v[3]);
    *(uint2*)(sPw + lr * 128 + ((nb * 32 + lg * 8) ^ ((lr & 7) << 4))) = w;
  }
#pragma unroll
  for (int kk = 0; kk < 2; ++kk)
    qlo[kk] = *(const bf16x8*)(sPw + lr * 128 +
                               ((kk * 64 + lg * 16) ^ ((lr & 7) << 4)));

  f32x4 Oacc[4];
#pragma unroll
  for (int db = 0; db < 4; ++db) Oacc[db] = (f32x4){0.f, 0.f, 0.f, 0.f};
  float m_r = -3.0e38f, l_r = 0.f;
  int buf = 0;

  // ---- main loop: one barrier per KV tile, async blob prefetch ----
  for (int t = 0; t < nT; ++t) {
    if (t + 1 < nT) STAGE(t + 1, (buf ^ 1) * 8192);
    const int bK = buf * 8192;
    const int kv0 = t * 64;

    if (kv0 <= q0 + wave * 16 + 15) {  // wave-uniform causal activity
      // ---- QK^T swapped (split, 24 MFMA): sacc[nb][r]=S[kv...][qrow] ----
      f32x4 sacc[4];
#pragma unroll
      for (int nb = 0; nb < 4; ++nb) sacc[nb] = (f32x4){0.f, 0.f, 0.f, 0.f};
#pragma unroll
      for (int nb = 0; nb < 4; ++nb) {
        int krow = nb * 16 + lr;
#pragma unroll
        for (int kk = 0; kk < 2; ++kk) {
          int off = krow * 128 + ((kk * 64 + lg * 16) ^ ((krow & 7) << 4));
          bf16x8 kh = *(const bf16x8*)(smem + bK + off);
          bf16x8 kl = *(const bf16x8*)(smem + 16384 + bK + off);
          sacc[nb] = MFMA16(kh, qhi[kk], sacc[nb]);
          sacc[nb] = MFMA16(kl, qhi[kk], sacc[nb]);
          sacc[nb] = MFMA16(kh, qlo[kk], sacc[nb]);
        }
      }

      // ---- causal mask (diagonal-adjacent tiles only) ----
      if (kv0 + 63 > q0 + wave * 16) {
#pragma unroll
        for (int nb = 0; nb < 4; ++nb)
#pragma unroll
          for (int r = 0; r < 4; ++r)
            if (kv0 + nb * 16 + lg * 4 + r > qrow) sacc[nb][r] = -1.0e30f;
      }

      // ---- per-lane online softmax (log2 domain) with defer-max ----
      float tmax = sacc[0][0];
#pragma unroll
      for (int nb = 0; nb < 4; ++nb)
#pragma unroll
        for (int r = 0; r < 4; ++r) tmax = fmaxf(tmax, sacc[nb][r]);
      tmax = fmaxf(tmax, __shfl_xor(tmax, 16));
      tmax = fmaxf(tmax, __shfl_xor(tmax, 32));
      if (!__all(tmax <= m_r + 8.0f)) {
        float mn = fmaxf(m_r, tmax);
        float corr = exp2f(m_r - mn);
        m_r = mn;
        l_r *= corr;
#pragma unroll
        for (int db = 0; db < 4; ++db) Oacc[db] *= corr;
      }
      float rs = 0.f;
#pragma unroll
      for (int nb = 0; nb < 4; ++nb)
#pragma unroll
        for (int r = 0; r < 4; ++r) {
          float e = exp2f(sacc[nb][r] - m_r);
          sacc[nb][r] = e;
          rs += e;
        }
      rs += __shfl_xor(rs, 16);
      rs += __shfl_xor(rs, 32);
      l_r += rs;

      // ---- P -> sP (4 b64 writes via v_cvt_pk) -> B-fragments ----
#pragma unroll
      for (int nb = 0; nb < 4; ++nb) {
        uint2 w;
        w.x = cvtpk(sacc[nb][0], sacc[nb][1]);
        w.y = cvtpk(sacc[nb][2], sacc[nb][3]);
        *(uint2*)(sPw + lr * 128 + ((nb * 32 + lg * 8) ^ ((lr & 7) << 4))) = w;
      }
      bf16x8 pa[2];
#pragma unroll
      for (int kk = 0; kk < 2; ++kk)
        pa[kk] = *(const bf16x8*)(sPw + lr * 128 +
                                  ((kk * 64 + lg * 16) ^ ((lr & 7) << 4)));

      // ---- PV swapped: Oacc[db][r] = O[qrow][db*16+lg*4+r] ----
#pragma unroll
      for (int db = 0; db < 4; ++db) {
        int vrow = db * 16 + lr;
#pragma unroll
        for (int kk = 0; kk < 2; ++kk) {
          int off = vrow * 128 + ((kk * 64 + lg * 16) ^ ((vrow & 7) << 4));
          bf16x8 vb = *(const bf16x8*)(smem + 32768 + bK + off);
          Oacc[db] = MFMA16(vb, pa[kk], Oacc[db]);
        }
      }
    }

    __syncthreads();  // drains prefetch (vmcnt) + publishes buffer swap
    buf ^= 1;
  }

  // ---- epilogue: coalesced float4 stores ----
  float invl = 1.0f / l_r;
  float* orow = Out + ((size_t)bh * S_LEN + qrow) * 64;
#pragma unroll
  for (int db = 0; db < 4; ++db) {
    float4 o = make_float4(Oacc[db][0] * invl, Oacc[db][1] * invl,
                           Oacc[db][2] * invl, Oacc[db][3] * invl);
    *(float4*)(orow + db * 16 + lg * 4) = o;
  }
#undef STAGE
}

extern "C" void kernel_launch(void* const* d_in, const int* in_sizes, int n_in,
                              void* d_out, int out_size, void* d_ws,
                              size_t ws_size, hipStream_t stream) {
  const float* Hin = (const float*)d_in[0];
  const float* Hk = (const float*)d_in[1];
  const float* Hv = (const float*)d_in[2];
  // d_in[3] = mask (analytic), d_in[5] = F_hidden (=64)
  const float* avAp = (const float*)d_in[4];
  float* Out = (float*)d_out;

  const size_t N = (size_t)NBH * S_LEN * 64;  // 4,194,304 elems per tensor
  u16* Khb = (u16*)d_ws;                      // 8 MB
  u16* Klb = Khb + N;                         // 8 MB
  u16* Vtb = Klb + N;                         // 8 MB

  prep_kernel<<<dim3(S_LEN / 64, NBH), dim3(256), 0, stream>>>(Hk, Hv, Khb,
                                                               Klb, Vtb);
  attn_kernel<<<dim3(S_LEN / 128, NBH), dim3(512), 0, stream>>>(
      Hin, avAp, Khb, Klb, Vtb, Out);
}